// Round 4
// baseline (1205.371 us; speedup 1.0000x reference)
//
#include <hip/hip_runtime.h>

// ---- shapes (hard-coded) ----
#define TT 64
#define CONCAT 1536
#define ROWSH 1792                 // shorts per x row: 1280 hist + 2*256 o double-buf
#define X_SHORTS (16 * ROWSH)      // 28672 shorts = 57344 B
#define PS 260                     // partial row stride (floats) -> bank-skewed
#define PBLK (16 * PS)             // floats per kq block

typedef __attribute__((ext_vector_type(8))) short bf16x8;
typedef __attribute__((ext_vector_type(4))) short short4v;
typedef __attribute__((ext_vector_type(4))) float float4v;

__device__ __forceinline__ short f2bf(float f) {
    union { float f; unsigned u; } v;
    v.f = f;
    unsigned r = v.u + 0x7fffu + ((v.u >> 16) & 1u);  // RNE
    return (short)(r >> 16);
}

// Repack W (256x1536 fp32) -> bf16 MFMA-B-fragment order:
// frag (tl 0..15, kb 0..47): lane L holds W[tl*16+(L&15)][kb*32+(L>>4)*8+j], j=0..7.
__global__ void wprep_kernel(const float* __restrict__ W, short* __restrict__ Wb) {
    int idx = blockIdx.x * 256 + threadIdx.x;       // 0 .. 49151
    if (idx >= 16 * 48 * 64) return;
    int lane = idx & 63;
    int kb   = (idx >> 6) % 48;
    int tl   = idx / (48 * 64);
    int n = tl * 16 + (lane & 15);
    int k = kb * 32 + (lane >> 4) * 8;
    const float* src = W + (size_t)n * CONCAT + k;
    short4v s0, s1;
    s0.x = f2bf(src[0]); s0.y = f2bf(src[1]); s0.z = f2bf(src[2]); s0.w = f2bf(src[3]);
    s1.x = f2bf(src[4]); s1.y = f2bf(src[5]); s1.z = f2bf(src[6]); s1.w = f2bf(src[7]);
    short* dst = Wb + (size_t)idx * 8;
    *(short4v*)dst = s0;
    *(short4v*)(dst + 4) = s1;
}

// s_waitcnt immediate (gfx9): vmcnt[3:0], exp[6:4]=7, lgkm[11:8]=0xF free
#define WAIT_VM(n)   __builtin_amdgcn_s_waitcnt(0x0F70 | (n))

// 64 WGs x 1024 thr (16 waves). WG = 16 seqs. wave = (ng: 4 out-tiles of 16) x (kq: K/4).
// W: global->VGPR double-buffered, vmcnt-paced (never touches LDS).
// x: XOR-swizzled LDS (granule ^ (row&7)), conflict-free A-frag b128 reads.
__global__ __launch_bounds__(1024) void hist_kernel(
    const float* __restrict__ o,    // (B,T,P,256)
    const float* __restrict__ act,  // (B,T,P,64)
    const float* __restrict__ bias, // (256)
    const short* __restrict__ Wb,   // packed bf16 B-frags [tl][kb][lane][8]
    float* __restrict__ out)        // (B,T,P,256)
{
    __shared__ short lds[X_SHORTS + 2 * 4 * PBLK];   // x (57344B) + partial (66560B)

    const int tid  = threadIdx.x;
    const int wave = tid >> 6;
    const int lane = tid & 63;
    const int q    = lane >> 4;
    const int ln   = lane & 15;
    const int lnx  = ln & 7;
    const int ng   = wave >> 2;
    const int kq   = wave & 3;
    const int bb   = blockIdx.x >> 2;
    const int p0   = (blockIdx.x & 3) << 4;

    float* part = (float*)&lds[X_SHORTS];

    // zero z/a history (granules 0..159 of each row)
    for (int g = tid; g < 16 * 160; g += 1024) {
        int row = g / 160, gg = g - row * 160;
        *(float4v*)&lds[row * ROWSH + gg * 8] = (float4v){0.f, 0.f, 0.f, 0.f};
    }

    // W stream pointers: wave's 4 tiles at its K-quarter
    const short* wp0 = Wb + ((size_t)(((ng * 4 + 0) * 48) + kq * 12) * 64 + lane) * 8;
    const short* wp1 = Wb + ((size_t)(((ng * 4 + 1) * 48) + kq * 12) * 64 + lane) * 8;
    const short* wp2 = Wb + ((size_t)(((ng * 4 + 2) * 48) + kq * 12) * 64 + lane) * 8;
    const short* wp3 = Wb + ((size_t)(((ng * 4 + 3) * 48) + kq * 12) * 64 + lane) * 8;

    // reduce/staging ids: thread = (seq s=wave, outs n0..n0+3)
    const int s   = wave;
    const int c64 = lane;
    const int n0  = c64 << 2;
    const int sx  = s & 7;
    const float4v bias4 = ((const float4v*)bias)[c64];

    const size_t tokbase = ((size_t)bb * TT) * 64 + p0;

    // prefetch t=0
    float4v ov = *(const float4v*)(o + (tokbase + s) * 256 + n0);
    float   av = act[(tokbase + s) * 64 + c64];
    float   avn;

    bf16x8 breg[2][4];
    int aoff[12];

    for (int t = 0; t < TT; ++t) {
        const size_t tok = tokbase + (size_t)t * 64;

        // ---- stage o_t (regs -> swizzled LDS o-buf, parity t&1) ----
        {
            int gl = 160 + (t & 1) * 32 + (n0 >> 3);
            short4v sv;
            sv.x = f2bf(ov.x); sv.y = f2bf(ov.y); sv.z = f2bf(ov.z); sv.w = f2bf(ov.w);
            *(short4v*)&lds[s * ROWSH + ((gl ^ sx) << 3) + (n0 & 7)] = sv;
        }
        __syncthreads();   // alpha: o_t + prev z/a slot writes visible (drains vmcnt)

        // ---- prefetch o/a for t+1 (oldest in vmcnt queue) ----
        {
            int t1 = (t + 1 < TT) ? t + 1 : t;
            const size_t tokn = tokbase + (size_t)t1 * 64;
            ov  = *(const float4v*)(o + (tokn + s) * 256 + n0);
            avn = act[(tokn + s) * 64 + c64];
        }

        // ---- B prologue: stages 0,1 in flight ----
        breg[0][0] = *(const bf16x8*)(wp0);
        breg[0][1] = *(const bf16x8*)(wp1);
        breg[0][2] = *(const bf16x8*)(wp2);
        breg[0][3] = *(const bf16x8*)(wp3);
        breg[1][0] = *(const bf16x8*)(wp0 + 512);
        breg[1][1] = *(const bf16x8*)(wp1 + 512);
        breg[1][2] = *(const bf16x8*)(wp2 + 512);
        breg[1][3] = *(const bf16x8*)(wp3 + 512);

        // ---- A-frag LDS offsets (shorts) for this wave's 12 k-blocks ----
        {
            const int ob = 160 + (t & 1) * 32;
#pragma unroll
            for (int j = 0; j < 12; ++j) {
                int kb = kq * 12 + j;
                int h = kb / 10, r = kb - h * 10;
                int G = (kb < 40)
                        ? (((h + t) & 3) * 40 + (r < 8 ? r * 4 : 32 + (r - 8) * 4))
                        : (ob + (kb - 40) * 4);
                aoff[j] = ln * ROWSH + (((G + q) ^ lnx) << 3);
            }
        }

        float4v acc0 = {0.f, 0.f, 0.f, 0.f};
        float4v acc1 = acc0, acc2 = acc0, acc3 = acc0;

#define KJ(j, nwait) { \
        WAIT_VM(nwait); \
        bf16x8 af = *(const bf16x8*)&lds[aoff[(j)]]; \
        acc0 = __builtin_amdgcn_mfma_f32_16x16x32_bf16(af, breg[(j)&1][0], acc0, 0, 0, 0); \
        acc1 = __builtin_amdgcn_mfma_f32_16x16x32_bf16(af, breg[(j)&1][1], acc1, 0, 0, 0); \
        acc2 = __builtin_amdgcn_mfma_f32_16x16x32_bf16(af, breg[(j)&1][2], acc2, 0, 0, 0); \
        acc3 = __builtin_amdgcn_mfma_f32_16x16x32_bf16(af, breg[(j)&1][3], acc3, 0, 0, 0); \
        if ((j) + 2 < 12) { \
            breg[(j)&1][0] = *(const bf16x8*)(wp0 + ((j)+2) * 512); \
            breg[(j)&1][1] = *(const bf16x8*)(wp1 + ((j)+2) * 512); \
            breg[(j)&1][2] = *(const bf16x8*)(wp2 + ((j)+2) * 512); \
            breg[(j)&1][3] = *(const bf16x8*)(wp3 + ((j)+2) * 512); \
        } }

        KJ(0, 4)  KJ(1, 4)  KJ(2, 4)  KJ(3, 4)  KJ(4, 4)  KJ(5, 4)
        KJ(6, 4)  KJ(7, 4)  KJ(8, 4)  KJ(9, 4)  KJ(10, 4) KJ(11, 0)
#undef KJ

        // ---- partial writes: part[kq][row m][col n] ----
        {
            float* pw = part + kq * PBLK + (q * 4) * PS + (ng << 6) + ln;
            pw[0 * PS +  0] = acc0[0]; pw[1 * PS +  0] = acc0[1];
            pw[2 * PS +  0] = acc0[2]; pw[3 * PS +  0] = acc0[3];
            pw[0 * PS + 16] = acc1[0]; pw[1 * PS + 16] = acc1[1];
            pw[2 * PS + 16] = acc1[2]; pw[3 * PS + 16] = acc1[3];
            pw[0 * PS + 32] = acc2[0]; pw[1 * PS + 32] = acc2[1];
            pw[2 * PS + 32] = acc2[2]; pw[3 * PS + 32] = acc2[3];
            pw[0 * PS + 48] = acc3[0]; pw[1 * PS + 48] = acc3[1];
            pw[2 * PS + 48] = acc3[2]; pw[3 * PS + 48] = acc3[3];
        }
        __syncthreads();   // beta: partials visible; slot (t&3) reads done

        // ---- reduce + epilogue ----
        {
            float4v z = bias4;
#pragma unroll
            for (int k = 0; k < 4; ++k) {
                float4v pv = *(const float4v*)&part[k * PBLK + s * PS + n0];
                z.x += pv.x; z.y += pv.y; z.z += pv.z; z.w += pv.w;
            }
            *(float4v*)(out + (tok + s) * 256 + n0) = z;

            const int pzg = (t & 3) * 40;    // slot granule base
            short4v sv;
            sv.x = f2bf(z.x); sv.y = f2bf(z.y); sv.z = f2bf(z.z); sv.w = f2bf(z.w);
            *(short4v*)&lds[s * ROWSH + (((pzg + (n0 >> 3)) ^ sx) << 3) + (n0 & 7)] = sv;
            lds[s * ROWSH + (((pzg + 32 + (c64 >> 3)) ^ sx) << 3) + (c64 & 7)] = f2bf(av);
        }
        av = avn;
        // next alpha orders slot writes before the next MFMA phase
    }
}

extern "C" void kernel_launch(void* const* d_in, const int* in_sizes, int n_in,
                              void* d_out, int out_size, void* d_ws, size_t ws_size,
                              hipStream_t stream) {
    const float* o  = (const float*)d_in[0];
    const float* a  = (const float*)d_in[1];
    const float* W  = (const float*)d_in[2];
    const float* b  = (const float*)d_in[3];
    short* Wb = (short*)d_ws;   // 786432 B used

    hipLaunchKernelGGL(wprep_kernel, dim3(192), dim3(256), 0, stream, W, Wb);
    hipLaunchKernelGGL(hist_kernel, dim3(64), dim3(1024), 0, stream,
                       o, a, b, Wb, (float*)d_out);
}